// Round 6
// baseline (620.469 us; speedup 1.0000x reference)
//
#include <hip/hip_runtime.h>
#include <math.h>

// Qwen3.5 TopK Router, MI355X. fp64-accumulated GEMM for exact index ordering.
// logits = X(T,D) @ W(E,D)^T ; softmax over E; top-8 + renormalize.
// Out layout (all fp32): [T*E softmax-probs | T*K weights | T*K indices-as-float]
//
// R6 vs R5 (390us, LDS-instr-throughput-bound) / R4 (329us, 52% VALU busy):
//  - Back to BM=64 + 4x8 thread tile + fp32 LDS (R4's balance: LDS ~123us
//    < VALU ~155us), but 1024-thread blocks with split-K x4 (256 thr/group,
//    512 k each, BK=16 so 4 groups fit 48KB LDS) -> 16 waves/CU = 4/SIMD.
//  - Conflict-free layouts:
//    A: k-major pitch 64, token-XOR phi(k)=((k>>2)&3)<<4 (stores 2-way free,
//       reads 4-addr broadcast free).
//    B: interleaved pos(e)=(e&3)+4*(e>>3)+64*((e>>2)&1), XOR psi(k)=
//       ((k>>2)&3)<<2. Reads: 16 lanes x 16B tile a full 1KB row -> free.
//  - fp64 partial exchange through LDS (two 32-token rounds), then R4's
//    verified epilogue on group 0. Extra fp64 adds: ~1e-15, indices safe.

constexpr int T = 16384;
constexpr int D = 2048;
constexpr int E = 128;
constexpr int K = 8;

constexpr int BM = 64;    // tokens per block
constexpr int BK = 16;    // k-chunk per stage
constexpr int NG = 4;     // k-split groups
constexpr int KG = D / NG;            // 512 k per group
constexpr int GSZ = BK * BM + BK * E; // floats per group region: 1024+2048

__global__ __launch_bounds__(1024, 1)
void router_fused(const float* __restrict__ X,
                  const float* __restrict__ W,
                  float* __restrict__ out)
{
    __shared__ float smem_f[NG * GSZ];   // 48 KB

    const int tid = threadIdx.x;
    const int g   = tid >> 8;            // k-group 0..3
    const int l   = tid & 255;           // lane within group
    const int tx  = l & 15;              // expert group (8 experts)
    const int ty  = l >> 4;              // token group (4 tokens)
    const long t0 = (long)blockIdx.x * BM;

    float* As = smem_f + g * GSZ;        // [k][tok^phi(k)], pitch 64
    float* Bs = As + BK * BM;            // [k][pos(e)^psi(k)], pitch 128

    double acc[4][8];
#pragma unroll
    for (int i = 0; i < 4; ++i)
#pragma unroll
        for (int j = 0; j < 8; ++j) acc[i][j] = 0.0;

    // A staging: tok = l>>2 (0..63), q = l&3 -> float4 X[tok][kb+4q]
    const int a_tok = l >> 2, a_q = l & 3;
    // B staging: e = l>>1 (0..127), h = l&1 -> float4s W[e][kb+8h+{0,4}]
    const int b_e = l >> 1, b_h = l & 1;
    const int b_pos = (b_e & 3) + ((b_e >> 3) << 2) + (((b_e >> 2) & 1) << 6);

    const long kg0 = (long)g * KG;
    const float* Xp = X + (t0 + a_tok) * D + kg0 + (a_q << 2);
    const float* Wp = W + (long)b_e * D + kg0 + (b_h << 3);

    // prologue loads
    float4 xa  = *(const float4*)(Xp);
    float4 wb0 = *(const float4*)(Wp);
    float4 wb1 = *(const float4*)(Wp + 4);

    for (int k0 = 0; k0 < KG; k0 += BK) {
        __syncthreads();   // previous tile fully consumed
        {
            // A store: k = 4*a_q + c -> phi = a_q<<4 (same for c=0..3)
            const int tA = a_tok ^ (a_q << 4);
            float* Ap = As + (a_q << 2) * BM;
            Ap[0 * BM + tA] = xa.x; Ap[1 * BM + tA] = xa.y;
            Ap[2 * BM + tA] = xa.z; Ap[3 * BM + tA] = xa.w;
            // B store: f4 #0 -> q = 2*b_h, f4 #1 -> q = 2*b_h+1
            {
                const int q0 = (b_h << 1), q1 = (b_h << 1) + 1;
                const int p0 = b_pos ^ (q0 << 2);
                const int p1 = b_pos ^ (q1 << 2);
                float* Bp0 = Bs + (q0 << 2) * E;
                float* Bp1 = Bs + (q1 << 2) * E;
                Bp0[0 * E + p0] = wb0.x; Bp0[1 * E + p0] = wb0.y;
                Bp0[2 * E + p0] = wb0.z; Bp0[3 * E + p0] = wb0.w;
                Bp1[0 * E + p1] = wb1.x; Bp1[1 * E + p1] = wb1.y;
                Bp1[2 * E + p1] = wb1.z; Bp1[3 * E + p1] = wb1.w;
            }
        }
        __syncthreads();

        // prefetch next tile while computing this one
        const int kn = k0 + BK;
        if (kn < KG) {
            xa  = *(const float4*)(Xp + kn);
            wb0 = *(const float4*)(Wp + kn);
            wb1 = *(const float4*)(Wp + kn + 4);
        }

#pragma unroll
        for (int kk = 0; kk < BK; ++kk) {
            const int psiA = ((kk >> 2) & 3) << 4;
            const int psiB = ((kk >> 2) & 3) << 2;
            const int bb   = (tx << 2) ^ psiB;
            float4 av  = *(const float4*)&As[kk * BM + ((ty << 2) ^ psiA)];
            float4 bv0 = *(const float4*)&Bs[kk * E + bb];
            float4 bv1 = *(const float4*)&Bs[kk * E + bb + 64];
            const double a[4] = {(double)av.x, (double)av.y, (double)av.z, (double)av.w};
            const double b[8] = {(double)bv0.x, (double)bv0.y, (double)bv0.z, (double)bv0.w,
                                 (double)bv1.x, (double)bv1.y, (double)bv1.z, (double)bv1.w};
#pragma unroll
            for (int i = 0; i < 4; ++i)
#pragma unroll
                for (int j = 0; j < 8; ++j)
                    acc[i][j] = fma(a[i], b[j], acc[i][j]);
        }
    }

    // ---- cross-group reduction into group 0, two 32-token rounds ----
    double* ex = (double*)smem_f;        // 32 tok x 128 exp = 32 KB
    __syncthreads();                     // all groups done with tile buffers
#pragma unroll
    for (int half = 0; half < 2; ++half) {
        const bool mine = ((ty >> 3) == half);
        const int trow = ((ty & 7) << 2);
        if (g == 1 && mine) {
#pragma unroll
            for (int i = 0; i < 4; ++i)
#pragma unroll
                for (int j = 0; j < 8; ++j)
                    ex[(trow + i) * E + (tx << 3) + j] = acc[i][j];
        }
        __syncthreads();
        if (g == 2 && mine) {
#pragma unroll
            for (int i = 0; i < 4; ++i)
#pragma unroll
                for (int j = 0; j < 8; ++j)
                    ex[(trow + i) * E + (tx << 3) + j] += acc[i][j];
        }
        __syncthreads();
        if (g == 3 && mine) {
#pragma unroll
            for (int i = 0; i < 4; ++i)
#pragma unroll
                for (int j = 0; j < 8; ++j)
                    ex[(trow + i) * E + (tx << 3) + j] += acc[i][j];
        }
        __syncthreads();
        if (g == 0 && mine) {
#pragma unroll
            for (int i = 0; i < 4; ++i)
#pragma unroll
                for (int j = 0; j < 8; ++j)
                    acc[i][j] += ex[(trow + i) * E + (tx << 3) + j];
        }
        __syncthreads();
    }
    if (g != 0) return;                  // no barriers below

    float* outL  = out;
    float* outWt = out + (long)T * E;
    float* outId = outWt + (long)T * K;

    // epilogue (group 0): each token row = 16 lanes (same ty, all tx) of one wave
    for (int i = 0; i < 4; ++i) {
        const long t = t0 + (ty << 2) + i;

        double m = acc[i][0];
#pragma unroll
        for (int j = 1; j < 8; ++j) m = fmax(m, acc[i][j]);
#pragma unroll
        for (int mask = 1; mask <= 8; mask <<= 1)
            m = fmax(m, __shfl_xor(m, mask, 64));

        float e[8]; float s = 0.f;
#pragma unroll
        for (int j = 0; j < 8; ++j) { e[j] = __expf((float)(acc[i][j] - m)); s += e[j]; }
#pragma unroll
        for (int mask = 1; mask <= 8; mask <<= 1)
            s += __shfl_xor(s, mask, 64);
        const float inv = 1.f / s;

        float p[8];
#pragma unroll
        for (int j = 0; j < 8; ++j) p[j] = e[j] * inv;

        float4 st0 = {p[0], p[1], p[2], p[3]};
        float4 st1 = {p[4], p[5], p[6], p[7]};
        *(float4*)&outL[t * E + (tx << 3)]     = st0;
        *(float4*)&outL[t * E + (tx << 3) + 4] = st1;

        // top-8 on fp64 LOGITS (value desc, index asc) == jax.lax.top_k order
        double v[8];
#pragma unroll
        for (int j = 0; j < 8; ++j) v[j] = acc[i][j];

        float pk[K]; int ik[K]; float tsum = 0.f;
#pragma unroll
        for (int r = 0; r < K; ++r) {
            double bv = -1.0e300; int bi = 0x7fffffff;
#pragma unroll
            for (int j = 0; j < 8; ++j) {
                const int idx = (tx << 3) + j;
                const bool better = (v[j] > bv) || (v[j] == bv && idx < bi);
                bv = better ? v[j] : bv;
                bi = better ? idx : bi;
            }
#pragma unroll
            for (int mask = 1; mask <= 8; mask <<= 1) {
                const double ov = __shfl_xor(bv, mask, 64);
                const int    oi = __shfl_xor(bi, mask, 64);
                const bool better = (ov > bv) || (ov == bv && oi < bi);
                bv = better ? ov : bv;
                bi = better ? oi : bi;
            }
            const float pw = __expf((float)(bv - m)) * inv;
            pk[r] = pw; ik[r] = bi; tsum += pw;
            if ((bi >> 3) == tx) v[bi & 7] = -1.0e300;
        }

        if (tx == 0) {
            const float rinv = 1.f / tsum;
#pragma unroll
            for (int r = 0; r < K; ++r) {
                outWt[t * K + r] = pk[r] * rinv;
                outId[t * K + r] = (float)ik[r];
            }
        }
    }
}

extern "C" void kernel_launch(void* const* d_in, const int* in_sizes, int n_in,
                              void* d_out, int out_size, void* d_ws, size_t ws_size,
                              hipStream_t stream)
{
    const float* X = (const float*)d_in[0];
    const float* W = (const float*)d_in[1];
    float* out = (float*)d_out;
    router_fused<<<dim3(T / BM), dim3(1024), 0, stream>>>(X, W, out);
}

// Round 7
// 391.708 us; speedup vs baseline: 1.5840x; 1.5840x over previous
//
#include <hip/hip_runtime.h>
#include <math.h>

// Qwen3.5 TopK Router, MI355X. fp64-accumulated GEMM for exact index ordering.
// logits = X(T,D) @ W(E,D)^T ; softmax over E; top-8 + renormalize.
// Out layout (all fp32): [T*E softmax-probs | T*K weights | T*K indices-as-float]
//
// R7 vs R6 (513us: launch_bounds(1024,1) -> 64-VGPR cap -> acc spilled to
// scratch, 2.2GB writes) and R4 (329us: 2 waves/SIMD but one shared barrier):
//  - grid-level split-K x2: 512 blocks (= 2 INDEPENDENT 256-thread blocks/CU,
//    own barriers -> one computes while the other stages). launch_bounds(256,2)
//    = 128-VGPR cap; acc(64) + prefetch + addr fits, no spill.
//  - kernel 1 writes fp64 partial logits to d_ws (2 x T x E doubles = 33.6 MB);
//    kernel 2 (256 blocks) adds the two partials and runs the R4-verified
//    softmax/top-8 epilogue. Same two-term fp64 sum as R4 -> absmax identical.
//  - A: R3 phi-swizzle (stores 2-way free). B: R6 interleaved layout
//    pos(e)=(e&3)+4*(e>>3)+64*((e>>2)&1), psi(k)=((k>>2)&3)<<2 -> b128 reads
//    2-way free, stores 4-way (measured cheap: 4.9e6 conflict cycles in R6).

constexpr int T = 16384;
constexpr int D = 2048;
constexpr int E = 128;
constexpr int K = 8;

constexpr int BM = 64;    // tokens per block
constexpr int BK = 32;    // k-chunk
constexpr int KH = D / 2; // k per split-K half

__global__ __launch_bounds__(256, 2)
void router_gemm(const float* __restrict__ X,
                 const float* __restrict__ W,
                 double* __restrict__ ws)
{
    __shared__ float As[BK * BM];   // [k][tok ^ phi(k)]      8 KB
    __shared__ float Bs[BK * E];    // [k][pos(e) ^ psi(k)]  16 KB

    const int tid = threadIdx.x;
    const int g   = blockIdx.x & 1;             // k-half
    const long t0 = (long)(blockIdx.x >> 1) * BM;
    const int tx  = tid & 15;                   // expert group (8 experts)
    const int ty  = tid >> 4;                   // token group (4 tokens)

    double acc[4][8];
#pragma unroll
    for (int i = 0; i < 4; ++i)
#pragma unroll
        for (int j = 0; j < 8; ++j) acc[i][j] = 0.0;

    const int ar = tid >> 3;            // 0..31
    const int ac = (tid & 7) << 2;      // 0,4,...,28
    const int phiS = ((ac >> 2) & 3) << 3;   // A-store token XOR
    const int psiS = ((ac >> 2) & 3) << 2;   // B-store pos XOR

    const float* Xp = X + (t0 + ar) * D + (long)g * KH + ac;
    const float* Wp = W + (long)ar * D + (long)g * KH + ac;

    // prologue: tile 0
    float4 a0 = *(const float4*)(Xp);
    float4 a1 = *(const float4*)(Xp + 32L * D);
    float4 b0 = *(const float4*)(Wp);
    float4 b1 = *(const float4*)(Wp + 32L * D);
    float4 b2 = *(const float4*)(Wp + 64L * D);
    float4 b3 = *(const float4*)(Wp + 96L * D);

    for (int k0 = 0; k0 < KH; k0 += BK) {
        __syncthreads();   // previous tile fully consumed
        {
            const int cA0 = ar ^ phiS, cA1 = (ar + 32) ^ phiS;
            As[(ac+0)*BM + cA0] = a0.x; As[(ac+1)*BM + cA0] = a0.y;
            As[(ac+2)*BM + cA0] = a0.z; As[(ac+3)*BM + cA0] = a0.w;
            As[(ac+0)*BM + cA1] = a1.x; As[(ac+1)*BM + cA1] = a1.y;
            As[(ac+2)*BM + cA1] = a1.z; As[(ac+3)*BM + cA1] = a1.w;

            // B interleave: pos(e) = (e&3) + 4*(e>>3) + 64*((e>>2)&1)
            const int e0 = ar, e1 = ar + 32, e2 = ar + 64, e3 = ar + 96;
            const int p0 = ((e0&3) + ((e0>>3)<<2) + (((e0>>2)&1)<<6)) ^ psiS;
            const int p1 = ((e1&3) + ((e1>>3)<<2) + (((e1>>2)&1)<<6)) ^ psiS;
            const int p2 = ((e2&3) + ((e2>>3)<<2) + (((e2>>2)&1)<<6)) ^ psiS;
            const int p3 = ((e3&3) + ((e3>>3)<<2) + (((e3>>2)&1)<<6)) ^ psiS;
            Bs[(ac+0)*E + p0] = b0.x; Bs[(ac+1)*E + p0] = b0.y;
            Bs[(ac+2)*E + p0] = b0.z; Bs[(ac+3)*E + p0] = b0.w;
            Bs[(ac+0)*E + p1] = b1.x; Bs[(ac+1)*E + p1] = b1.y;
            Bs[(ac+2)*E + p1] = b1.z; Bs[(ac+3)*E + p1] = b1.w;
            Bs[(ac+0)*E + p2] = b2.x; Bs[(ac+1)*E + p2] = b2.y;
            Bs[(ac+2)*E + p2] = b2.z; Bs[(ac+3)*E + p2] = b2.w;
            Bs[(ac+0)*E + p3] = b3.x; Bs[(ac+1)*E + p3] = b3.y;
            Bs[(ac+2)*E + p3] = b3.z; Bs[(ac+3)*E + p3] = b3.w;
        }
        __syncthreads();

        // prefetch next tile while computing this one
        const int kn = k0 + BK;
        if (kn < KH) {
            a0 = *(const float4*)(Xp + kn);
            a1 = *(const float4*)(Xp + kn + 32L * D);
            b0 = *(const float4*)(Wp + kn);
            b1 = *(const float4*)(Wp + kn + 32L * D);
            b2 = *(const float4*)(Wp + kn + 64L * D);
            b3 = *(const float4*)(Wp + kn + 96L * D);
        }

#pragma unroll
        for (int kk = 0; kk < BK; ++kk) {
            const int phi = ((kk >> 2) & 3) << 3;
            const int psi = ((kk >> 2) & 3) << 2;
            const int bb  = (tx << 2) ^ psi;   // experts 8tx..8tx+3 ; +64 -> 8tx+4..7
            float4 av  = *(const float4*)&As[kk*BM + ((ty << 2) ^ phi)];
            float4 bv0 = *(const float4*)&Bs[kk*E + bb];
            float4 bv1 = *(const float4*)&Bs[kk*E + bb + 64];
            const double a[4] = {(double)av.x, (double)av.y, (double)av.z, (double)av.w};
            const double b[8] = {(double)bv0.x, (double)bv0.y, (double)bv0.z, (double)bv0.w,
                                 (double)bv1.x, (double)bv1.y, (double)bv1.z, (double)bv1.w};
#pragma unroll
            for (int i = 0; i < 4; ++i)
#pragma unroll
                for (int j = 0; j < 8; ++j)
                    acc[i][j] = fma(a[i], b[j], acc[i][j]);
        }
    }

    // write fp64 partials to workspace: ws[g][t][e]
#pragma unroll
    for (int i = 0; i < 4; ++i) {
        const long t = t0 + (ty << 2) + i;
        double* dst = ws + ((long)g * T + t) * E + (tx << 3);
        *(double2*)(dst + 0) = make_double2(acc[i][0], acc[i][1]);
        *(double2*)(dst + 2) = make_double2(acc[i][2], acc[i][3]);
        *(double2*)(dst + 4) = make_double2(acc[i][4], acc[i][5]);
        *(double2*)(dst + 6) = make_double2(acc[i][6], acc[i][7]);
    }
}

__global__ __launch_bounds__(256, 4)
void router_epilogue(const double* __restrict__ ws,
                     float* __restrict__ out)
{
    const int tid = threadIdx.x;
    const int tx  = tid & 15;
    const int ty  = tid >> 4;
    const long t0 = (long)blockIdx.x * BM;

    double acc[4][8];
#pragma unroll
    for (int i = 0; i < 4; ++i) {
        const long t = t0 + (ty << 2) + i;
        const double* s0 = ws + t * E + (tx << 3);
        const double* s1 = s0 + (long)T * E;
#pragma unroll
        for (int h = 0; h < 4; ++h) {
            double2 u = *(const double2*)(s0 + 2*h);
            double2 v = *(const double2*)(s1 + 2*h);
            acc[i][2*h+0] = u.x + v.x;
            acc[i][2*h+1] = u.y + v.y;
        }
    }

    float* outL  = out;
    float* outWt = out + (long)T * E;
    float* outId = outWt + (long)T * K;

    for (int i = 0; i < 4; ++i) {
        const long t = t0 + (ty << 2) + i;

        double m = acc[i][0];
#pragma unroll
        for (int j = 1; j < 8; ++j) m = fmax(m, acc[i][j]);
#pragma unroll
        for (int mask = 1; mask <= 8; mask <<= 1)
            m = fmax(m, __shfl_xor(m, mask, 64));

        float e[8]; float s = 0.f;
#pragma unroll
        for (int j = 0; j < 8; ++j) { e[j] = __expf((float)(acc[i][j] - m)); s += e[j]; }
#pragma unroll
        for (int mask = 1; mask <= 8; mask <<= 1)
            s += __shfl_xor(s, mask, 64);
        const float inv = 1.f / s;

        float p[8];
#pragma unroll
        for (int j = 0; j < 8; ++j) p[j] = e[j] * inv;

        float4 st0 = {p[0], p[1], p[2], p[3]};
        float4 st1 = {p[4], p[5], p[6], p[7]};
        *(float4*)&outL[t * E + (tx << 3)]     = st0;
        *(float4*)&outL[t * E + (tx << 3) + 4] = st1;

        // top-8 on fp64 LOGITS (value desc, index asc) == jax.lax.top_k order
        double v[8];
#pragma unroll
        for (int j = 0; j < 8; ++j) v[j] = acc[i][j];

        float pk[K]; int ik[K]; float tsum = 0.f;
#pragma unroll
        for (int r = 0; r < K; ++r) {
            double bv = -1.0e300; int bi = 0x7fffffff;
#pragma unroll
            for (int j = 0; j < 8; ++j) {
                const int idx = (tx << 3) + j;
                const bool better = (v[j] > bv) || (v[j] == bv && idx < bi);
                bv = better ? v[j] : bv;
                bi = better ? idx : bi;
            }
#pragma unroll
            for (int mask = 1; mask <= 8; mask <<= 1) {
                const double ov = __shfl_xor(bv, mask, 64);
                const int    oi = __shfl_xor(bi, mask, 64);
                const bool better = (ov > bv) || (ov == bv && oi < bi);
                bv = better ? ov : bv;
                bi = better ? oi : bi;
            }
            const float pw = __expf((float)(bv - m)) * inv;
            pk[r] = pw; ik[r] = bi; tsum += pw;
            if ((bi >> 3) == tx) v[bi & 7] = -1.0e300;
        }

        if (tx == 0) {
            const float rinv = 1.f / tsum;
#pragma unroll
            for (int r = 0; r < K; ++r) {
                outWt[t * K + r] = pk[r] * rinv;
                outId[t * K + r] = (float)ik[r];
            }
        }
    }
}

extern "C" void kernel_launch(void* const* d_in, const int* in_sizes, int n_in,
                              void* d_out, int out_size, void* d_ws, size_t ws_size,
                              hipStream_t stream)
{
    const float* X = (const float*)d_in[0];
    const float* W = (const float*)d_in[1];
    float* out = (float*)d_out;
    double* ws = (double*)d_ws;   // needs 2 * T * E * 8 = 33.6 MB
    router_gemm<<<dim3(2 * (T / BM)), dim3(256), 0, stream>>>(X, W, ws);
    router_epilogue<<<dim3(T / BM), dim3(256), 0, stream>>>(ws, out);
}